// Round 14
// baseline (264.910 us; speedup 1.0000x reference)
//
#include <hip/hip_runtime.h>
#include <hip/hip_bf16.h>

typedef unsigned short ushort_t;
typedef unsigned int uint_t;
typedef __attribute__((ext_vector_type(8))) short short8;
typedef __attribute__((ext_vector_type(4))) float float4v;
typedef __attribute__((ext_vector_type(16))) float float16v;
typedef __attribute__((ext_vector_type(4))) uint_t uint4v;

#define NLAT 2048
#define DLAT 64

// d_ws layout (ushort units): [0..127] flag area (int at byte 0), then packed
// weights as 32x32x16 A-fragments. L0: 8mt x 13kt, L1-3: 8mt x 16kt frags,
// each frag 64 lanes x 16B.
#define PW_BASE 128
#define PW0_OFF 0          // 8*13*512 = 53248 ushorts
#define PW1_OFF 53248      // 8*16*512 = 65536 each
#define PW2_OFF 118784
#define PW3_OFF 184320

__device__ __forceinline__ float b2f(ushort_t u) {
  union { uint_t i; float f; } v; v.i = ((uint_t)u) << 16; return v.f;
}
__device__ __forceinline__ ushort_t f2b(float f) {
  uint_t x = __float_as_uint(f);
  uint_t r = (x + 0x7fffu + ((x >> 16) & 1u)) >> 16;   // RNE
  return (ushort_t)r;
}
// HW packed f32x2 -> bf16x2 (v_cvt_pk_bf16_f32)
__device__ __forceinline__ uint_t pack2(float lo, float hi) {
  float2 t; t.x = lo; t.y = hi;
  union { __hip_bfloat162 h; uint_t u; } cv;
  cv.h = __float22bfloat162_rn(t);
  return cv.u;
}
__device__ __forceinline__ int imin(int a, int b) { return a < b ? a : b; }
__device__ __forceinline__ int imax(int a, int b) { return a > b ? a : b; }

__device__ __forceinline__ float ldv(const float* p, long i)    { return p[i]; }
__device__ __forceinline__ float ldv(const ushort_t* p, long i) { return b2f(p[i]); }
__device__ __forceinline__ void stv(float* p, long i, float v)    { p[i] = v; }
__device__ __forceinline__ void stv(ushort_t* p, long i, float v) { p[i] = f2b(v); }

__device__ __forceinline__ float4 load4f(const float* p) { return *(const float4*)p; }
__device__ __forceinline__ float4 load4f(const ushort_t* p) {
  uint2 u = *(const uint2*)p;
  float4 r;
  r.x = b2f((ushort_t)(u.x & 0xffffu)); r.y = b2f((ushort_t)(u.x >> 16));
  r.z = b2f((ushort_t)(u.y & 0xffffu)); r.w = b2f((ushort_t)(u.y >> 16));
  return r;
}

// async 16B/lane global->LDS copy (gfx950 global_load_lds_dwordx4)
__device__ __forceinline__ void async_copy16(const ushort_t* g, ushort_t* l) {
  __builtin_amdgcn_global_load_lds(
      (const __attribute__((address_space(1))) void*)g,
      (__attribute__((address_space(3))) void*)l, 16, 0, 0);
}

// Stage one weight quarter (2 mt32-tiles): KT*2*64 16B units. 256 threads.
__device__ __forceinline__ void stage_gi(int gi, ushort_t* dst,
                                         const ushort_t* __restrict__ pw, int tid) {
  int layer = gi >> 2, qq = gi & 3;
  const ushort_t* src; int n;
  if (layer == 0) { src = pw + PW0_OFF + (size_t)qq * 13312; n = 1664; }
  else {
    int loff = (layer == 1) ? PW1_OFF : (layer == 2) ? PW2_OFF : PW3_OFF;
    src = pw + loff + (size_t)qq * 16384; n = 2048;
  }
  for (int i = tid; i < n; i += 256)
    async_copy16(src + (size_t)i * 8, dst + (size_t)i * 8);
}

// ---------------------------------------------------------------------------
// Runtime dtype probe: flag=1 -> fp32 inputs, flag=0 -> bf16
// ---------------------------------------------------------------------------
__global__ void detect_mode(const ushort_t* __restrict__ lat, int* __restrict__ flag) {
  if (threadIdx.x == 0) *flag = 0;
  __syncthreads();
  int big = 0;
  for (int i = threadIdx.x; i < 1024; i += 64) {
    float v = b2f(lat[i]);
    if (!(fabsf(v) < 1e5f)) big = 1;
  }
  if (__any(big) && threadIdx.x == 0) *flag = 1;
}

// ---------------------------------------------------------------------------
// Pack weights as 32x32x16 MFMA A-fragments (A = W^T, m = chan_out):
//   frag(mt,kt,lane)[j] = W[chan(k)][mt*32 + (lane&31)],
//   k = 16*kt + 8*(lane>>5) + j.
// Layers 1-3: chan(k) = pi^-1(k): blk=k>>5, kl=k&31, t=(kl>>4)&1, h2=(kl>>3)&1,
//   u=(kl>>2)&1, b=kl&3 -> chan = 32*blk + 8*(2t+u) + 4*h2 + b.
// (pi matches the 32x32 C-layout register order so convert is in-lane.)
// Layer 0: k indexes the permuted feature vector
//   [sampled(192) | coord | pe(12) | pad->208], mapped back to W0 rows.
// ---------------------------------------------------------------------------
template <typename TI>
__global__ void pack_w_t(const TI* __restrict__ W0, const TI* __restrict__ W1,
                         const TI* __restrict__ W2, const TI* __restrict__ W3,
                         ushort_t* __restrict__ pw, const int* __restrict__ flag, int want)
{
  if (*flag != want) return;
  int g = blockIdx.x * blockDim.x + threadIdx.x;
  if (g >= 488 * 64) return;
  int lane = g & 63, h = lane >> 5;
  int fid  = g >> 6;                        // 0..487
  const TI* W; ushort_t* dst; int mt, kt, KTL, layer;
  if (fid < 104) { layer = 0; W = W0; dst = pw + PW0_OFF; mt = fid / 13; kt = fid % 13; KTL = 13; }
  else {
    int f2 = fid - 104;
    layer = 1 + f2 / 128;
    int r = f2 & 127; mt = r >> 4; kt = r & 15; KTL = 16;
    W = (layer == 1) ? W1 : (layer == 2) ? W2 : W3;
    dst = pw + ((layer == 1) ? PW1_OFF : (layer == 2) ? PW2_OFF : PW3_OFF);
  }
  int col = mt * 32 + (lane & 31);
  uint_t words[4];
#pragma unroll
  for (int hw = 0; hw < 4; ++hw) {
    ushort_t vv[2];
#pragma unroll
    for (int e = 0; e < 2; ++e) {
      int j = 2 * hw + e;
      int k = 16 * kt + 8 * h + j;
      int row;
      if (layer == 0) {
        row = (k < 192) ? (13 + k) : (k == 192 ? 0 : (k <= 204 ? k - 192 : -1));
      } else {
        int blk = k >> 5, kl = k & 31;
        int t = (kl >> 4) & 1, h2 = (kl >> 3) & 1, u = (kl >> 2) & 1, b = kl & 3;
        row = 32 * blk + 8 * (2 * t + u) + 4 * h2 + b;
      }
      vv[e] = (row >= 0) ? f2b(ldv(W, (long)row * 256 + col)) : (ushort_t)0;
    }
    words[hw] = (uint_t)vv[0] | ((uint_t)vv[1] << 16);
  }
  uint4 o; o.x = words[0]; o.y = words[1]; o.z = words[2]; o.w = words[3];
  *(uint4*)(dst + ((size_t)(mt * KTL + kt) * 64 + lane) * 8) = o;
}

// ---------------------------------------------------------------------------
// One layer = 4 quarter-passes (2 mt32-tiles each) from ping-ponged 32KB LDS
// buffers; stage quarter gi+1 while computing gi. 32x32x16 MFMA: 2 ds_read +
// 2 MFMA per kt-step (software-pipelined aL/aH).
// ---------------------------------------------------------------------------
template <int KT, int BASE>
__device__ __forceinline__ void run_layer(float16v (&acc)[8],
                                          const uint4v (&hu)[16],
                                          ushort_t (*wbuf)[16384],
                                          const ushort_t* __restrict__ pw,
                                          int tid, int lane)
{
#pragma unroll
  for (int qq = 0; qq < 4; ++qq) {
    constexpr int KTC = KT;
    const int gi = BASE + qq;
    if (gi + 1 < 16) stage_gi(gi + 1, wbuf[(gi + 1) & 1], pw, tid);
    const ushort_t* buf = wbuf[gi & 1];
    float16v c0, c1;
#pragma unroll
    for (int i = 0; i < 16; ++i) { c0[i] = 0.f; c1[i] = 0.f; }
    short8 aL, aH;
    aL = *(const short8*)&buf[((size_t)(0 * KTC + 0) * 64 + lane) * 8];
#pragma unroll
    for (int kt = 0; kt < KTC; ++kt) {
      aH = *(const short8*)&buf[((size_t)(1 * KTC + kt) * 64 + lane) * 8];
      short8 b = __builtin_bit_cast(short8, hu[kt]);
      c0 = __builtin_amdgcn_mfma_f32_32x32x16_bf16(aL, b, c0, 0, 0, 0);
      if (kt + 1 < KTC)
        aL = *(const short8*)&buf[((size_t)(0 * KTC + kt + 1) * 64 + lane) * 8];
      c1 = __builtin_amdgcn_mfma_f32_32x32x16_bf16(aH, b, c1, 0, 0, 0);
    }
    acc[2 * qq]     = c0;
    acc[2 * qq + 1] = c1;
    __syncthreads();
  }
}

// acc -> bias+relu+bf16 pack -> hu (next layer's B operand, pi order: acc reg
// rr of mt-tile -> frag 2*mt+(rr>>3), element rr&7 — pure in-lane repack).
__device__ __forceinline__ void convert_layer(float16v (&acc)[8], uint4v (&hu)[16],
                                              const float* bwl, int h)
{
#pragma unroll
  for (int mt = 0; mt < 8; ++mt) {
#pragma unroll
    for (int a = 0; a < 4; ++a) {
      float4 bv = *(const float4*)&bwl[32 * mt + 8 * a + 4 * h];
#pragma unroll
      for (int b2 = 0; b2 < 2; ++b2) {
        int rr = 4 * a + 2 * b2;
        float v0 = fmaxf(acc[mt][rr]     + ((const float*)&bv)[2 * b2],     0.f);
        float v1 = fmaxf(acc[mt][rr + 1] + ((const float*)&bv)[2 * b2 + 1], 0.f);
        hu[2 * mt + (rr >> 3)][(rr & 7) >> 1] = pack2(v0, v1);
      }
    }
  }
}

// ---------------------------------------------------------------------------
// Fused kernel. 256 threads = 4 waves; wave owns 32 points (n = lane&31,
// lane>>5 selects the k-half). TWO independent blocks per CU. Activations in
// registers; weights stream through 2x32KB LDS quarter buffers.
// ---------------------------------------------------------------------------
template <typename TI>
__global__ __launch_bounds__(256, 2) void lisa_fused_t(
    const TI* __restrict__ coord, const TI* __restrict__ latent,
    const TI* __restrict__ bias0, const TI* __restrict__ bias1,
    const TI* __restrict__ bias2, const TI* __restrict__ bias3,
    const TI* __restrict__ W4,    const TI* __restrict__ b4,
    const ushort_t* __restrict__ pw, TI* __restrict__ out,
    const int* __restrict__ flag, int want)
{
  if (*flag != want) return;
  __shared__ __align__(16) ushort_t wbuf[2][16384];      // 2 x 32 KB quarters
  __shared__ __align__(16) float bw[4 * 256 + 256 + 1];  // biases | w4 | b4

  const int tid  = threadIdx.x;
  const int lane = tid & 63, h = lane >> 5, n32 = lane & 31;
  const int wv   = tid >> 6;                              // 0..3
  const long p   = (long)blockIdx.x * 128 + wv * 32 + n32;

  // ---- stage L0 quarter 0 (async) + bias/w4 table ----
  stage_gi(0, wbuf[0], pw, tid);
  for (int i = tid; i < 1281; i += 256) {
    float v;
    if (i < 256)       v = ldv(bias0, i);
    else if (i < 512)  v = ldv(bias1, i - 256);
    else if (i < 768)  v = ldv(bias2, i - 512);
    else if (i < 1024) v = ldv(bias3, i - 768);
    else if (i < 1280) v = ldv(W4, i - 1024);
    else               v = ldv(b4, 0);
    bw[i] = v;
  }

  // ---- feature build into B-frags: lane holds k = 16kt+8h+j of its point ----
  uint4v hu[16];
  {
    float c   = ldv(coord, p);
    float ixv = c * 2048.0f - 0.5f;
    float x0f = floorf(ixv);
    float t   = ixv - x0f;
    int   x0  = (int)x0f;
    int   i0  = imin(imax(x0, 0), NLAT - 1);
    int   i1  = imin(imax(x0 + 1, 0), NLAT - 1);
    float w0 = 1.0f - t, w1 = t;
    int rows0[3] = { imax(i0 - 1, 0), i0, imin(i0 + 1, NLAT - 1) };
    int rows1[3] = { imax(i1 - 1, 0), i1, imin(i1 + 1, NLAT - 1) };
    const TI* lat = latent + (size_t)(p >> 15) * (NLAT * DLAT);
#pragma unroll
    for (int kt = 0; kt < 12; ++kt) {          // sampled features f<192
      int f0 = 16 * kt + 8 * h;
      int region = f0 >> 6, d0 = f0 & 63;
      float4 a0 = load4f(lat + (long)rows0[region] * DLAT + d0);
      float4 a1 = load4f(lat + (long)rows0[region] * DLAT + d0 + 4);
      float4 b0 = load4f(lat + (long)rows1[region] * DLAT + d0);
      float4 b1 = load4f(lat + (long)rows1[region] * DLAT + d0 + 4);
      hu[kt][0] = pack2(w0 * a0.x + w1 * b0.x, w0 * a0.y + w1 * b0.y);
      hu[kt][1] = pack2(w0 * a0.z + w1 * b0.z, w0 * a0.w + w1 * b0.w);
      hu[kt][2] = pack2(w0 * a1.x + w1 * b1.x, w0 * a1.y + w1 * b1.y);
      hu[kt][3] = pack2(w0 * a1.z + w1 * b1.z, w0 * a1.w + w1 * b1.w);
    }
    // kt=12: f = 192+8h+j -> [coord | pe(12) | pad]
    float e[8];
#pragma unroll
    for (int j = 0; j < 8; ++j) {
      int f = 192 + 8 * h + j;
      float v = 0.0f;
      if (f == 192) v = c;
      else if (f <= 204) {
        int i = f - 193;
        float fr = (float)(1 << (i >> 1));
        float ang = c * fr;
        v = (i & 1) ? __cosf(ang) : __sinf(ang);
      }
      e[j] = v;
    }
    hu[12][0] = pack2(e[0], e[1]);
    hu[12][1] = pack2(e[2], e[3]);
    hu[12][2] = pack2(e[4], e[5]);
    hu[12][3] = pack2(e[6], e[7]);
  }
  __syncthreads();   // quarter 0 ready (vmcnt drained at barrier), table ready

  float16v acc[8];

  run_layer<13,  0>(acc, hu, wbuf, pw, tid, lane);
  convert_layer(acc, hu, bw + 0 * 256, h);
  run_layer<16,  4>(acc, hu, wbuf, pw, tid, lane);
  convert_layer(acc, hu, bw + 1 * 256, h);
  run_layer<16,  8>(acc, hu, wbuf, pw, tid, lane);
  convert_layer(acc, hu, bw + 2 * 256, h);
  run_layer<16, 12>(acc, hu, wbuf, pw, tid, lane);

  // ---- final: bias3+relu + 256->1 dot against w4 ----
  float partial = 0.f;
#pragma unroll
  for (int mt = 0; mt < 8; ++mt) {
#pragma unroll
    for (int a = 0; a < 4; ++a) {
      float4 b3v = *(const float4*)&bw[3 * 256 + 32 * mt + 8 * a + 4 * h];
      float4 w4v = *(const float4*)&bw[1024 + 32 * mt + 8 * a + 4 * h];
#pragma unroll
      for (int e = 0; e < 4; ++e) {
        int rr = 4 * a + e;
        float v = fmaxf(acc[mt][rr] + ((const float*)&b3v)[e], 0.f);
        partial += v * ((const float*)&w4v)[e];
      }
    }
  }
  partial += __shfl_xor(partial, 32, 64);   // combine the two k-halves
  if (lane < 32) stv(out, p, partial + bw[1280]);
}

extern "C" void kernel_launch(void* const* d_in, const int* in_sizes, int n_in,
                              void* d_out, int out_size, void* d_ws, size_t ws_size,
                              hipStream_t stream) {
  int* flag = (int*)d_ws;
  ushort_t* pw = (ushort_t*)d_ws + PW_BASE;

  detect_mode<<<1, 64, 0, stream>>>((const ushort_t*)d_in[1], flag);

  // fp32-input variant (flag==1)
  pack_w_t<float><<<61, 512, 0, stream>>>(
      (const float*)d_in[2], (const float*)d_in[4], (const float*)d_in[6],
      (const float*)d_in[8], pw, flag, 1);
  lisa_fused_t<float><<<2048, 256, 0, stream>>>(
      (const float*)d_in[0], (const float*)d_in[1],
      (const float*)d_in[3], (const float*)d_in[5], (const float*)d_in[7],
      (const float*)d_in[9], (const float*)d_in[10], (const float*)d_in[11],
      pw, (float*)d_out, flag, 1);

  // bf16-input variant (flag==0)
  pack_w_t<ushort_t><<<61, 512, 0, stream>>>(
      (const ushort_t*)d_in[2], (const ushort_t*)d_in[4], (const ushort_t*)d_in[6],
      (const ushort_t*)d_in[8], pw, flag, 0);
  lisa_fused_t<ushort_t><<<2048, 256, 0, stream>>>(
      (const ushort_t*)d_in[0], (const ushort_t*)d_in[1],
      (const ushort_t*)d_in[3], (const ushort_t*)d_in[5], (const ushort_t*)d_in[7],
      (const ushort_t*)d_in[9], (const ushort_t*)d_in[10], (const ushort_t*)d_in[11],
      pw, (ushort_t*)d_out, flag, 0);
}

// Round 15
// 224.575 us; speedup vs baseline: 1.1796x; 1.1796x over previous
//
#include <hip/hip_runtime.h>
#include <hip/hip_bf16.h>

typedef unsigned short ushort_t;
typedef unsigned int uint_t;
typedef __attribute__((ext_vector_type(8))) short short8;
typedef __attribute__((ext_vector_type(4))) float float4v;
typedef __attribute__((ext_vector_type(4))) uint_t uint4v;

#define NLAT 2048
#define DLAT 64

// d_ws layout (ushort units): [0..127] flag area (int at byte 0), then packed weights
#define PW_BASE 128
#define PW0_OFF 0        // layer0: KT=7 -> 7*16*64*8 = 57344 ushorts
#define PW1_OFF 57344    // KT=8 -> 65536 each
#define PW2_OFF 122880
#define PW3_OFF 188416

__device__ __forceinline__ float b2f(ushort_t u) {
  union { uint_t i; float f; } v; v.i = ((uint_t)u) << 16; return v.f;
}
__device__ __forceinline__ ushort_t f2b(float f) {
  uint_t x = __float_as_uint(f);
  uint_t r = (x + 0x7fffu + ((x >> 16) & 1u)) >> 16;   // RNE
  return (ushort_t)r;
}
// HW packed f32x2 -> bf16x2 (v_cvt_pk_bf16_f32)
__device__ __forceinline__ uint_t pack2(float lo, float hi) {
  float2 t; t.x = lo; t.y = hi;
  union { __hip_bfloat162 h; uint_t u; } cv;
  cv.h = __float22bfloat162_rn(t);
  return cv.u;
}
__device__ __forceinline__ int imin(int a, int b) { return a < b ? a : b; }
__device__ __forceinline__ int imax(int a, int b) { return a > b ? a : b; }

__device__ __forceinline__ float ldv(const float* p, long i)    { return p[i]; }
__device__ __forceinline__ float ldv(const ushort_t* p, long i) { return b2f(p[i]); }
__device__ __forceinline__ void stv(float* p, long i, float v)    { p[i] = v; }
__device__ __forceinline__ void stv(ushort_t* p, long i, float v) { p[i] = f2b(v); }

__device__ __forceinline__ float4 load4f(const float* p) { return *(const float4*)p; }
__device__ __forceinline__ float4 load4f(const ushort_t* p) {
  uint2 u = *(const uint2*)p;
  float4 r;
  r.x = b2f((ushort_t)(u.x & 0xffffu)); r.y = b2f((ushort_t)(u.x >> 16));
  r.z = b2f((ushort_t)(u.y & 0xffffu)); r.w = b2f((ushort_t)(u.y >> 16));
  return r;
}

// async 16B/lane global->LDS copy (gfx950 global_load_lds_dwordx4)
__device__ __forceinline__ void async_copy16(const ushort_t* g, ushort_t* l) {
  __builtin_amdgcn_global_load_lds(
      (const __attribute__((address_space(1))) void*)g,
      (__attribute__((address_space(3))) void*)l, 16, 0, 0);
}

// Stage one weight quarter (KT*2048 ushorts) -> 32KB LDS buffer, 256 threads.
template <int KT>
__device__ __forceinline__ void stage_q_t(ushort_t* dst, const ushort_t* src, int tid) {
#pragma unroll
  for (int r = 0; r < KT; ++r) {
    int i = tid + (r << 8);
    async_copy16(src + (size_t)i * 8, dst + (size_t)i * 8);
  }
}
// gi is compile-time constant at all call sites (unrolled loops) -> folds.
__device__ __forceinline__ void stage_gi(int gi, ushort_t* dst,
                                         const ushort_t* __restrict__ pw, int tid) {
  int layer = gi >> 2, q = gi & 3;
  if (layer == 0) {
    stage_q_t<7>(dst, pw + PW0_OFF + q * 7 * 2048, tid);
  } else {
    int loff = (layer == 1) ? PW1_OFF : (layer == 2) ? PW2_OFF : PW3_OFF;
    stage_q_t<8>(dst, pw + loff + q * 8 * 2048, tid);
  }
}

// ---------------------------------------------------------------------------
// Runtime dtype probe: flag=1 -> fp32 inputs, flag=0 -> bf16
// ---------------------------------------------------------------------------
__global__ void detect_mode(const ushort_t* __restrict__ lat, int* __restrict__ flag) {
  if (threadIdx.x == 0) *flag = 0;
  __syncthreads();
  int big = 0;
  for (int i = threadIdx.x; i < 1024; i += 64) {
    float v = b2f(lat[i]);
    if (!(fabsf(v) < 1e5f)) big = 1;
  }
  if (__any(big) && threadIdx.x == 0) *flag = 1;
}

// ---------------------------------------------------------------------------
// Pack weights as MFMA A-fragments (A = W^T, m = chan_out), sigma k-permuted
// to match the C-register order of the previous layer:
//   element j of frag(mt,kt,lane) = W[sigma][mt*16 + (lane&15)]
//   sigma = 32*kt + 16*(j>>2) + 4*(lane>>4) + (j&3)
// Layer 0: sigma indexes [sampled(192) | coord | pe(12) | pad->224].
// ---------------------------------------------------------------------------
template <typename TI>
__global__ void pack_w_t(const TI* __restrict__ W0, const TI* __restrict__ W1,
                         const TI* __restrict__ W2, const TI* __restrict__ W3,
                         ushort_t* __restrict__ pw, const int* __restrict__ flag, int want)
{
  if (*flag != want) return;
  int g = blockIdx.x * blockDim.x + threadIdx.x;
  if (g >= 31 * 1024) return;
  int lane = g & 63, q = lane >> 4;
  int mt   = (g >> 6) & 15;
  int ktg  = g >> 10;                       // 0..30
  const TI* W; ushort_t* dst; int kt, KT; bool isw0 = false;
  if (ktg < 7)       { W = W0; dst = pw + PW0_OFF; kt = ktg;      KT = 7; isw0 = true; }
  else if (ktg < 15) { W = W1; dst = pw + PW1_OFF; kt = ktg - 7;  KT = 8; }
  else if (ktg < 23) { W = W2; dst = pw + PW2_OFF; kt = ktg - 15; KT = 8; }
  else               { W = W3; dst = pw + PW3_OFF; kt = ktg - 23; KT = 8; }
  int col = mt * 16 + (lane & 15);
  uint_t words[4];
#pragma unroll
  for (int h = 0; h < 4; ++h) {
    ushort_t vv[2];
#pragma unroll
    for (int e = 0; e < 2; ++e) {
      int j = 2 * h + e;
      int f = 32 * kt + 16 * (j >> 2) + 4 * q + (j & 3);
      int row = f;
      if (isw0) row = (f < 192) ? (13 + f) : (f == 192 ? 0 : (f <= 204 ? f - 192 : -1));
      vv[e] = (row >= 0) ? f2b(ldv(W, (long)row * 256 + col)) : (ushort_t)0;
    }
    words[h] = (uint_t)vv[0] | ((uint_t)vv[1] << 16);
  }
  uint4 o; o.x = words[0]; o.y = words[1]; o.z = words[2]; o.w = words[3];
  *(uint4*)(dst + ((size_t)(mt * KT + kt) * 64 + lane) * 8) = o;
}

// ---------------------------------------------------------------------------
// One layer = 4 quarter-passes (4 mt-tiles each) from ping-ponged 32KB LDS
// buffers; stage quarter gi+1 while computing gi.
// K-loop software-pipelined with two alternating half-buffers (aL: mt 0-1,
// aH: mt 2-3) so ds_reads of one half overlap MFMAs of the other.
// ---------------------------------------------------------------------------
template <int KT>
__device__ __forceinline__ void run_layer(int base, float4v (&acc)[16][2],
                                          const uint4v (&hu)[8][2],
                                          ushort_t (*wbuf)[16384],
                                          const ushort_t* __restrict__ pw,
                                          int tid, int lane)
{
#pragma unroll
  for (int qq = 0; qq < 4; ++qq) {
    const int gi = base + qq;
    if (gi + 1 < 16) stage_gi(gi + 1, wbuf[(gi + 1) & 1], pw, tid);
    const ushort_t* buf = wbuf[gi & 1];
#pragma unroll
    for (int m = 0; m < 4; ++m) {
      acc[qq * 4 + m][0] = (float4v){0.f, 0.f, 0.f, 0.f};
      acc[qq * 4 + m][1] = (float4v){0.f, 0.f, 0.f, 0.f};
    }
    short8 aL[2], aH[2];
    aL[0] = *(const short8*)&buf[((size_t)(0 * KT + 0) * 64 + lane) * 8];
    aL[1] = *(const short8*)&buf[((size_t)(1 * KT + 0) * 64 + lane) * 8];
#pragma unroll
    for (int kt = 0; kt < KT; ++kt) {
      aH[0] = *(const short8*)&buf[((size_t)(2 * KT + kt) * 64 + lane) * 8];
      aH[1] = *(const short8*)&buf[((size_t)(3 * KT + kt) * 64 + lane) * 8];
      short8 b0 = __builtin_bit_cast(short8, hu[kt][0]);
      short8 b1 = __builtin_bit_cast(short8, hu[kt][1]);
      acc[qq * 4 + 0][0] = __builtin_amdgcn_mfma_f32_16x16x32_bf16(aL[0], b0, acc[qq * 4 + 0][0], 0, 0, 0);
      acc[qq * 4 + 0][1] = __builtin_amdgcn_mfma_f32_16x16x32_bf16(aL[0], b1, acc[qq * 4 + 0][1], 0, 0, 0);
      acc[qq * 4 + 1][0] = __builtin_amdgcn_mfma_f32_16x16x32_bf16(aL[1], b0, acc[qq * 4 + 1][0], 0, 0, 0);
      acc[qq * 4 + 1][1] = __builtin_amdgcn_mfma_f32_16x16x32_bf16(aL[1], b1, acc[qq * 4 + 1][1], 0, 0, 0);
      if (kt + 1 < KT) {
        aL[0] = *(const short8*)&buf[((size_t)(0 * KT + kt + 1) * 64 + lane) * 8];
        aL[1] = *(const short8*)&buf[((size_t)(1 * KT + kt + 1) * 64 + lane) * 8];
      }
      acc[qq * 4 + 2][0] = __builtin_amdgcn_mfma_f32_16x16x32_bf16(aH[0], b0, acc[qq * 4 + 2][0], 0, 0, 0);
      acc[qq * 4 + 2][1] = __builtin_amdgcn_mfma_f32_16x16x32_bf16(aH[0], b1, acc[qq * 4 + 2][1], 0, 0, 0);
      acc[qq * 4 + 3][0] = __builtin_amdgcn_mfma_f32_16x16x32_bf16(aH[1], b0, acc[qq * 4 + 3][0], 0, 0, 0);
      acc[qq * 4 + 3][1] = __builtin_amdgcn_mfma_f32_16x16x32_bf16(aH[1], b1, acc[qq * 4 + 3][1], 0, 0, 0);
    }
    __syncthreads();
  }
}

// acc -> bias+relu+bf16 pack -> hu (B operand of next layer, sigma order)
__device__ __forceinline__ void convert_layer(float4v (&acc)[16][2], uint4v (&hu)[8][2],
                                              const float* bwl, int q)
{
#pragma unroll
  for (int mt = 0; mt < 16; ++mt) {
    float4 b4 = *(const float4*)&bwl[mt * 16 + 4 * q];
#pragma unroll
    for (int g = 0; g < 2; ++g) {
      float v0 = fmaxf(acc[mt][g][0] + b4.x, 0.f);
      float v1 = fmaxf(acc[mt][g][1] + b4.y, 0.f);
      float v2 = fmaxf(acc[mt][g][2] + b4.z, 0.f);
      float v3 = fmaxf(acc[mt][g][3] + b4.w, 0.f);
      hu[mt >> 1][g][(mt & 1) * 2 + 0] = pack2(v0, v1);
      hu[mt >> 1][g][(mt & 1) * 2 + 1] = pack2(v2, v3);
    }
  }
}

// ---------------------------------------------------------------------------
// Fused kernel. 256 threads = 4 waves (wave owns 32 points); TWO independent
// blocks per CU so barriers/convert of one block overlap compute of the other.
// Activations in registers; weights stream through 2x32KB LDS quarter buffers.
// ---------------------------------------------------------------------------
template <typename TI>
__global__ __launch_bounds__(256, 2) void lisa_fused_t(
    const TI* __restrict__ coord, const TI* __restrict__ latent,
    const TI* __restrict__ bias0, const TI* __restrict__ bias1,
    const TI* __restrict__ bias2, const TI* __restrict__ bias3,
    const TI* __restrict__ W4,    const TI* __restrict__ b4,
    const ushort_t* __restrict__ pw, TI* __restrict__ out,
    const int* __restrict__ flag, int want)
{
  if (*flag != want) return;
  __shared__ __align__(16) ushort_t wbuf[2][16384];      // 2 x 32 KB quarters
  __shared__ __align__(16) float bw[4 * 256 + 256 + 1];  // biases | w4 | b4

  const int tid  = threadIdx.x;
  const int lane = tid & 63, q = lane >> 4, m15 = lane & 15;
  const int wv   = tid >> 6;                              // 0..3
  const long pbase = (long)blockIdx.x * 128 + wv * 32 + m15;  // group g adds 16

  // ---- stage L0 quarter 0 (async) + bias/w4 table ----
  stage_gi(0, wbuf[0], pw, tid);
  for (int i = tid; i < 1281; i += 256) {
    float v;
    if (i < 256)       v = ldv(bias0, i);
    else if (i < 512)  v = ldv(bias1, i - 256);
    else if (i < 768)  v = ldv(bias2, i - 512);
    else if (i < 1024) v = ldv(bias3, i - 768);
    else if (i < 1280) v = ldv(W4, i - 1024);
    else               v = ldv(b4, 0);
    bw[i] = v;
  }

  // ---- feature build directly into sigma-ordered B-frags (registers) ----
  uint4v hu[8][2];
#pragma unroll
  for (int g = 0; g < 2; ++g) {
    long p = pbase + g * 16;
    float c   = ldv(coord, p);
    float ixv = c * 2048.0f - 0.5f;
    float x0f = floorf(ixv);
    float t   = ixv - x0f;
    int   x0  = (int)x0f;
    int   i0  = imin(imax(x0, 0), NLAT - 1);
    int   i1  = imin(imax(x0 + 1, 0), NLAT - 1);
    float w0 = 1.0f - t, w1 = t;
    int rows0[3] = { imax(i0 - 1, 0), i0, imin(i0 + 1, NLAT - 1) };
    int rows1[3] = { imax(i1 - 1, 0), i1, imin(i1 + 1, NLAT - 1) };
    const TI* lat = latent + (size_t)(p >> 15) * (NLAT * DLAT);
#pragma unroll
    for (int tb = 0; tb < 12; ++tb) {
      int region = tb >> 2;
      int d0 = 16 * (tb & 3) + 4 * q;
      float4 a = load4f(lat + (long)rows0[region] * DLAT + d0);
      float4 b = load4f(lat + (long)rows1[region] * DLAT + d0);
      hu[tb >> 1][g][(tb & 1) * 2 + 0] = pack2(w0 * a.x + w1 * b.x, w0 * a.y + w1 * b.y);
      hu[tb >> 1][g][(tb & 1) * 2 + 1] = pack2(w0 * a.z + w1 * b.z, w0 * a.w + w1 * b.w);
    }
    float pv[4];
#pragma unroll
    for (int s = 0; s < 4; ++s) {
      int f = 192 + 4 * q + s;
      float v = 0.0f;
      if (f == 192) v = c;
      else if (f <= 204) {
        int i = f - 193;
        float fr = (float)(1 << (i >> 1));
        float ang = c * fr;
        v = (i & 1) ? __cosf(ang) : __sinf(ang);
      }
      pv[s] = v;
    }
    hu[6][g][0] = pack2(pv[0], pv[1]);
    hu[6][g][1] = pack2(pv[2], pv[3]);
    hu[6][g][2] = 0; hu[6][g][3] = 0;
  }
  __syncthreads();   // quarter 0 ready (vmcnt drained at barrier), table ready

  float4v acc[16][2];

  run_layer<7>( 0, acc, hu, wbuf, pw, tid, lane);
  convert_layer(acc, hu, bw + 0 * 256, q);
  run_layer<8>( 4, acc, hu, wbuf, pw, tid, lane);
  convert_layer(acc, hu, bw + 1 * 256, q);
  run_layer<8>( 8, acc, hu, wbuf, pw, tid, lane);
  convert_layer(acc, hu, bw + 2 * 256, q);
  run_layer<8>(12, acc, hu, wbuf, pw, tid, lane);

  // ---- final: bias3+relu fused with 256->1 dot against w4 ----
  float partial0 = 0.f, partial1 = 0.f;
#pragma unroll
  for (int mt = 0; mt < 16; ++mt) {
    float4 b3v = *(const float4*)&bw[3 * 256 + mt * 16 + 4 * q];
    float4 w4v = *(const float4*)&bw[1024 + mt * 16 + 4 * q];
    float v;
    v = fmaxf(acc[mt][0][0] + b3v.x, 0.f); partial0 += v * w4v.x;
    v = fmaxf(acc[mt][0][1] + b3v.y, 0.f); partial0 += v * w4v.y;
    v = fmaxf(acc[mt][0][2] + b3v.z, 0.f); partial0 += v * w4v.z;
    v = fmaxf(acc[mt][0][3] + b3v.w, 0.f); partial0 += v * w4v.w;
    v = fmaxf(acc[mt][1][0] + b3v.x, 0.f); partial1 += v * w4v.x;
    v = fmaxf(acc[mt][1][1] + b3v.y, 0.f); partial1 += v * w4v.y;
    v = fmaxf(acc[mt][1][2] + b3v.z, 0.f); partial1 += v * w4v.z;
    v = fmaxf(acc[mt][1][3] + b3v.w, 0.f); partial1 += v * w4v.w;
  }
  partial0 += __shfl_xor(partial0, 16, 64);
  partial0 += __shfl_xor(partial0, 32, 64);
  partial1 += __shfl_xor(partial1, 16, 64);
  partial1 += __shfl_xor(partial1, 32, 64);
  if (lane < 16) {
    float bb = bw[1280];
    stv(out, pbase,      partial0 + bb);
    stv(out, pbase + 16, partial1 + bb);
  }
}

extern "C" void kernel_launch(void* const* d_in, const int* in_sizes, int n_in,
                              void* d_out, int out_size, void* d_ws, size_t ws_size,
                              hipStream_t stream) {
  int* flag = (int*)d_ws;
  ushort_t* pw = (ushort_t*)d_ws + PW_BASE;

  detect_mode<<<1, 64, 0, stream>>>((const ushort_t*)d_in[1], flag);

  // fp32-input variant (flag==1)
  pack_w_t<float><<<62, 512, 0, stream>>>(
      (const float*)d_in[2], (const float*)d_in[4], (const float*)d_in[6],
      (const float*)d_in[8], pw, flag, 1);
  lisa_fused_t<float><<<2048, 256, 0, stream>>>(
      (const float*)d_in[0], (const float*)d_in[1],
      (const float*)d_in[3], (const float*)d_in[5], (const float*)d_in[7],
      (const float*)d_in[9], (const float*)d_in[10], (const float*)d_in[11],
      pw, (float*)d_out, flag, 1);

  // bf16-input variant (flag==0)
  pack_w_t<ushort_t><<<62, 512, 0, stream>>>(
      (const ushort_t*)d_in[2], (const ushort_t*)d_in[4], (const ushort_t*)d_in[6],
      (const ushort_t*)d_in[8], pw, flag, 0);
  lisa_fused_t<ushort_t><<<2048, 256, 0, stream>>>(
      (const ushort_t*)d_in[0], (const ushort_t*)d_in[1],
      (const ushort_t*)d_in[3], (const ushort_t*)d_in[5], (const ushort_t*)d_in[7],
      (const ushort_t*)d_in[9], (const ushort_t*)d_in[10], (const ushort_t*)d_in[11],
      pw, (ushort_t*)d_out, flag, 0);
}